// Round 7
// baseline (2154.870 us; speedup 1.0000x reference)
//
#include <hip/hip_runtime.h>

#define WDT 320
#define HGT 256
#define HWSZ 81920
#define NPIX 327680

__device__ __forceinline__ float sigm(float x){ return 1.0f/(1.0f + __expf(-x)); }
__device__ __forceinline__ float tanh_(float x){
  float e = __expf(-2.0f*fabsf(x));
  float t = (1.0f - e)/(1.0f + e);
  return x < 0.0f ? -t : t;
}

// ---------------- weight reorder (all f32): W[tap][cin][co] so co-rows broadcast from SGPRs
__global__ __launch_bounds__(256) void k_wprep(
    const float* __restrict__ zw, const float* __restrict__ rw,
    const float* __restrict__ qw, const float* __restrict__ d1w,
    const float* __restrict__ c1w, const float* __restrict__ d2w,
    const float* __restrict__ d3w,
    float* __restrict__ W1, float* __restrict__ W2, float* __restrict__ W3,
    float* __restrict__ Wd2, float* __restrict__ Wd3)
{
  const int N1 = 9*65*64, N2 = 9*65*32, N3 = 9*32*64, N4 = 32*64, N5 = 64*256;
  int i = blockIdx.x*256 + threadIdx.x;
  if (i < N1){
    int tc = i >> 6, co = i & 63;
    int tap = tc / 65, cin = tc % 65;
    float v = (co < 32) ? zw[(size_t)(co*65 + cin)*9 + tap]
                        : rw[(size_t)((co-32)*65 + cin)*9 + tap];
    W1[i] = v;
  } else if (i < N1 + N2){
    int j = i - N1;
    int tc = j >> 5, co = j & 31;
    int tap = tc / 65, cin = tc % 65;
    W2[j] = qw[(size_t)(co*65 + cin)*9 + tap];
  } else if (i < N1 + N2 + N3){
    int j = i - (N1 + N2);
    int tc = j >> 6, co = j & 63;
    int tap = tc >> 5, cin = tc & 31;
    float v = (co < 32) ? d1w[(size_t)(co*32 + cin)*9 + tap]
                        : c1w[(size_t)((co-32)*32 + cin)*9 + tap];
    W3[j] = v;
  } else if (i < N1 + N2 + N3 + N4){
    int j = i - (N1 + N2 + N3);
    int cin = j >> 6, co = j & 63;
    Wd2[j] = d2w[co*32 + cin];
  } else if (i < N1 + N2 + N3 + N4 + N5){
    int j = i - (N1 + N2 + N3 + N4);
    int cin = j >> 8, co = j & 255;
    Wd3[j] = d3w[co*64 + cin];
  }
}

// Conv kernels: round-0 chassis (pixel-per-thread, tap-outer, weights via
// s_load SGPR operands, 44 VGPR / 56% occupancy class — proven best).
// Round-6 lever: c-loop unroll 4/8 so 4-8 independent input loads (and
// their weight s_load streams) are in flight per exposed latency, instead
// of one. XCD band swizzle kept.

// ---------------- GRU part 1: conv(hx) -> z(32) | r(32); store z and r*hidden planes
__global__ __launch_bounds__(256) void k_gru1(
    const float* __restrict__ hidden, const float* __restrict__ ndp,
    const float* __restrict__ corr, const float* __restrict__ W1,
    const float* __restrict__ zb, const float* __restrict__ rb,
    float* __restrict__ zpl, float* __restrict__ rhpl)
{
  int bid = blockIdx.x;
  int pb = (bid & 7)*160 + (bid >> 3);
  int p = pb*256 + threadIdx.x;
  int row = p / WDT;
  int x = p - row*WDT;
  int yimg = row & (HGT-1);
  int b = row >> 8;
  size_t hbase = (size_t)b*32*HWSZ + (size_t)(p - b*HWSZ);
  float acc[64];
  #pragma unroll
  for (int i=0;i<64;++i) acc[i]=0.f;
  #pragma unroll
  for (int ty=0; ty<3; ++ty){
    int dy = ty-1;
    if ((unsigned)(yimg+dy) >= (unsigned)HGT) continue;   // uniform per wave
    #pragma unroll
    for (int tx=0; tx<3; ++tx){
      int dx = tx-1;
      bool okx = (unsigned)(x+dx) < (unsigned)WDT;
      int off = dy*WDT + dx;
      const float* wt = W1 + (ty*3+tx)*65*64;
      #pragma unroll 4
      for (int c=0;c<32;++c){
        float v = okx ? hidden[hbase + (size_t)c*HWSZ + off] : 0.f;
        const float* w = wt + c*64;
        #pragma unroll
        for (int i=0;i<64;++i) acc[i] = fmaf(w[i], v, acc[i]);
      }
      {
        float v = okx ? ndp[p + off] : 0.f;
        const float* w = wt + 32*64;
        #pragma unroll
        for (int i=0;i<64;++i) acc[i] = fmaf(w[i], v, acc[i]);
      }
      #pragma unroll 4
      for (int c=0;c<32;++c){
        float v = okx ? corr[hbase + (size_t)c*HWSZ + off] : 0.f;
        const float* w = wt + (33+c)*64;
        #pragma unroll
        for (int i=0;i<64;++i) acc[i] = fmaf(w[i], v, acc[i]);
      }
    }
  }
  #pragma unroll
  for (int c=0;c<32;++c)
    zpl[(size_t)c*NPIX + p] = sigm(acc[c] + zb[c]);
  #pragma unroll
  for (int c=0;c<32;++c){
    float r = sigm(acc[32+c] + rb[c]);
    rhpl[(size_t)c*NPIX + p] = r * hidden[hbase + (size_t)c*HWSZ];
  }
}

// ---------------- GRU part 2: q = tanh(conv([rh,nd,corr])); h = (1-z)h + z q -> d_out (NCHW)
__global__ __launch_bounds__(256) void k_gru2(
    const float* __restrict__ hidden, const float* __restrict__ ndp,
    const float* __restrict__ corr, const float* __restrict__ rhpl,
    const float* __restrict__ zpl, const float* __restrict__ W2,
    const float* __restrict__ qb, float* __restrict__ out_h)
{
  int bid = blockIdx.x;
  int pb = (bid & 7)*160 + (bid >> 3);
  int p = pb*256 + threadIdx.x;
  int row = p / WDT;
  int x = p - row*WDT;
  int yimg = row & (HGT-1);
  int b = row >> 8;
  size_t hbase = (size_t)b*32*HWSZ + (size_t)(p - b*HWSZ);
  float acc[32];
  #pragma unroll
  for (int i=0;i<32;++i) acc[i]=0.f;
  #pragma unroll
  for (int ty=0; ty<3; ++ty){
    int dy = ty-1;
    if ((unsigned)(yimg+dy) >= (unsigned)HGT) continue;
    #pragma unroll
    for (int tx=0; tx<3; ++tx){
      int dx = tx-1;
      bool okx = (unsigned)(x+dx) < (unsigned)WDT;
      int off = dy*WDT + dx;
      const float* wt = W2 + (ty*3+tx)*65*32;
      #pragma unroll 8
      for (int c=0;c<32;++c){
        float v = okx ? rhpl[(size_t)c*NPIX + p + off] : 0.f;
        const float* w = wt + c*32;
        #pragma unroll
        for (int i=0;i<32;++i) acc[i] = fmaf(w[i], v, acc[i]);
      }
      {
        float v = okx ? ndp[p + off] : 0.f;
        const float* w = wt + 32*32;
        #pragma unroll
        for (int i=0;i<32;++i) acc[i] = fmaf(w[i], v, acc[i]);
      }
      #pragma unroll 8
      for (int c=0;c<32;++c){
        float v = okx ? corr[hbase + (size_t)c*HWSZ + off] : 0.f;
        const float* w = wt + (33+c)*32;
        #pragma unroll
        for (int i=0;i<32;++i) acc[i] = fmaf(w[i], v, acc[i]);
      }
    }
  }
  #pragma unroll
  for (int c=0;c<32;++c){
    float qv = tanh_(acc[c] + qb[c]);
    float z  = zpl[(size_t)c*NPIX + p];
    float h0 = hidden[hbase + (size_t)c*HWSZ];
    out_h[hbase + (size_t)c*HWSZ] = (1.0f - z)*h0 + z*qv;
  }
}

// ---------------- heads conv: [dh1|ch1] 3x3 dil2 on h; t1 plane + conf/conf0
__global__ __launch_bounds__(256) void k_heads(
    const float* __restrict__ out_h, const float* __restrict__ W3,
    const float* __restrict__ c2w, const float* __restrict__ c2b,
    float* __restrict__ t1pl, float* __restrict__ out_conf, float* __restrict__ out_conf0)
{
  int bid = blockIdx.x;
  int pb = (bid & 7)*160 + (bid >> 3);
  int p = pb*256 + threadIdx.x;
  int row = p / WDT;
  int x = p - row*WDT;
  int yimg = row & (HGT-1);
  int b = row >> 8;
  size_t hbase = (size_t)b*32*HWSZ + (size_t)(p - b*HWSZ);
  float acc[64];
  #pragma unroll
  for (int i=0;i<64;++i) acc[i]=0.f;
  #pragma unroll
  for (int ty=0; ty<3; ++ty){
    int dy = (ty-1)*2;
    if ((unsigned)(yimg+dy) >= (unsigned)HGT) continue;
    #pragma unroll
    for (int tx=0; tx<3; ++tx){
      int dx = (tx-1)*2;
      bool okx = (unsigned)(x+dx) < (unsigned)WDT;
      int off = dy*WDT + dx;
      const float* wt = W3 + (ty*3+tx)*32*64;
      #pragma unroll 4
      for (int c=0;c<32;++c){
        float v = okx ? out_h[hbase + (size_t)c*HWSZ + off] : 0.f;
        const float* w = wt + c*64;
        #pragma unroll
        for (int i=0;i<64;++i) acc[i] = fmaf(w[i], v, acc[i]);
      }
    }
  }
  #pragma unroll
  for (int c=0;c<32;++c)
    t1pl[(size_t)c*NPIX + p] = fmaxf(acc[c], 0.f);
  float conf0 = c2b[0];
  #pragma unroll
  for (int i=0;i<32;++i)
    conf0 = fmaf(fmaxf(acc[32+i], 0.f), c2w[i], conf0);
  out_conf0[p] = conf0;
  out_conf[p]  = sigm(conf0);
}

// ---------------- depth tail: t2 = relu(Wd2 t1); logits = Wd3 t2 + b; softmax/argmax/nd
// Weight addresses wave-uniform via readfirstlane -> s_load broadcast.
__global__ __launch_bounds__(256) void k_depth(
    const float* __restrict__ t1pl, const float* __restrict__ Wd2,
    const float* __restrict__ Wd3, const float* __restrict__ d3b,
    float* __restrict__ out_prob, float* __restrict__ out_nd)
{
  __shared__ float t2l[64][65];
  __shared__ float redA[4][64];
  __shared__ int   redI[4][64];
  __shared__ float redB[4][64];
  __shared__ float redC[4][64];
  int tid = threadIdx.x, lane = tid & 63;
  int wvu = __builtin_amdgcn_readfirstlane(tid >> 6);
  int p = blockIdx.x*64 + lane;
  float a1[16];
  #pragma unroll
  for (int i=0;i<16;++i) a1[i]=0.f;
  const float* Wd2b = Wd2 + wvu*16;
  #pragma unroll 2
  for (int c=0;c<32;++c){
    float v = t1pl[(size_t)c*NPIX + p];
    const float* w = Wd2b + c*64;
    #pragma unroll
    for (int i=0;i<16;++i) a1[i] = fmaf(w[i], v, a1[i]);
  }
  #pragma unroll
  for (int i=0;i<16;++i) t2l[lane][wvu*16+i] = fmaxf(a1[i], 0.f);
  __syncthreads();
  float acc[64];
  #pragma unroll
  for (int i=0;i<64;++i) acc[i]=0.f;
  const float* Wd3b = Wd3 + wvu*64;
  #pragma unroll 2
  for (int c=0;c<64;++c){
    float v = t2l[lane][c];
    const float* w = Wd3b + c*256;
    #pragma unroll
    for (int i=0;i<64;++i) acc[i] = fmaf(w[i], v, acc[i]);
  }
  const float* bb = d3b + wvu*64;
  float mx = -1e30f; int am = 0;
  #pragma unroll
  for (int i=0;i<64;++i){
    float l = acc[i] + bb[i];
    acc[i] = l;
    if (l > mx){ mx = l; am = wvu*64+i; }
  }
  redA[wvu][lane] = mx; redI[wvu][lane] = am;
  __syncthreads();
  float gmx = redA[0][lane]; int gam = redI[0][lane];
  #pragma unroll
  for (int w2=1; w2<4; ++w2){
    float m = redA[w2][lane]; int a = redI[w2][lane];
    if (m > gmx || (m == gmx && a < gam)){ gmx = m; gam = a; }
  }
  float s = 0.f;
  #pragma unroll
  for (int i=0;i<64;++i){
    float e = __expf(acc[i] - gmx);
    acc[i] = e; s += e;
  }
  redB[wvu][lane] = s;
  __syncthreads();
  float gs = redB[0][lane] + redB[1][lane] + redB[2][lane] + redB[3][lane];
  float inv = 1.0f / gs;
  int b = p / HWSZ;
  int qq = p - b*HWSZ;
  size_t obase = (size_t)b*256*HWSZ + qq;
  int lo = gam - 4, hi = gam + 4;
  float num = 0.f, den = 0.f;
  #pragma unroll
  for (int i=0;i<64;++i){
    int m = wvu*64 + i;
    float pr = acc[i] * inv;
    out_prob[obase + (size_t)m*HWSZ] = pr;
    int mlt = (m >= lo && m <= hi) ? 1 : 0;
    if (m == 0 && lo < 0) mlt = 1 - lo;
    if (m == 255 && hi > 255) mlt = hi - 254;
    num += (float)(m*mlt) * pr;
    den += (float)mlt * pr;
  }
  redA[wvu][lane] = num; redC[wvu][lane] = den;
  __syncthreads();
  if (wvu == 0){
    float tn = redA[0][lane]+redA[1][lane]+redA[2][lane]+redA[3][lane];
    float td = redC[0][lane]+redC[1][lane]+redC[2][lane]+redC[3][lane];
    out_nd[p] = (tn / (1e-6f + td)) * (1.0f/255.0f);
  }
}

extern "C" void kernel_launch(void* const* d_in, const int* in_sizes, int n_in,
                              void* d_out, int out_size, void* d_ws, size_t ws_size,
                              hipStream_t stream)
{
  const float* hidden = (const float*)d_in[0];
  const float* ndp    = (const float*)d_in[1];
  const float* corr   = (const float*)d_in[2];
  const float* zw  = (const float*)d_in[3];
  const float* zb  = (const float*)d_in[4];
  const float* rw  = (const float*)d_in[5];
  const float* rb  = (const float*)d_in[6];
  const float* qw  = (const float*)d_in[7];
  const float* qb  = (const float*)d_in[8];
  const float* d1w = (const float*)d_in[9];
  const float* d2w = (const float*)d_in[10];
  const float* d3w = (const float*)d_in[11];
  const float* d3b = (const float*)d_in[12];
  const float* c1w = (const float*)d_in[13];
  const float* c2w = (const float*)d_in[14];
  const float* c2b = (const float*)d_in[15];
  float* out = (float*)d_out;

  float* ws   = (float*)d_ws;
  float* zpl  = ws;                   // 10,485,760 f32
  float* rhpl = ws + 10485760;        // 10,485,760
  float* t1pl = ws + 20971520;        // 10,485,760
  float* W1   = ws + 31457280;        // 37,440
  float* W2   = W1 + 37440;           // 18,720
  float* W3   = W2 + 18720;           // 18,432
  float* Wd2  = W3 + 18432;           // 2,048
  float* Wd3  = Wd2 + 2048;           // 16,384

  float* out_h     = out;
  float* out_nd    = out + 10485760;
  float* out_prob  = out + 10813440;
  float* out_conf  = out + 94699520;
  float* out_conf0 = out + 95027200;

  k_wprep<<<364, 256, 0, stream>>>(zw, rw, qw, d1w, c1w, d2w, d3w, W1, W2, W3, Wd2, Wd3);
  k_gru1 <<<NPIX/256, 256, 0, stream>>>(hidden, ndp, corr, W1, zb, rb, zpl, rhpl);
  k_gru2 <<<NPIX/256, 256, 0, stream>>>(hidden, ndp, corr, rhpl, zpl, W2, qb, out_h);
  k_heads<<<NPIX/256, 256, 0, stream>>>(out_h, W3, c2w, c2b, t1pl, out_conf, out_conf0);
  k_depth<<<NPIX/64, 256, 0, stream>>>(t1pl, Wd2, Wd3, d3b, out_prob, out_nd);
}

// Round 8
// 1200.792 us; speedup vs baseline: 1.7945x; 1.7945x over previous
//
#include <hip/hip_runtime.h>

#define WDT 320
#define HGT 256
#define HWSZ 81920
#define NPIX 327680

__device__ __forceinline__ float sigm(float x){ return 1.0f/(1.0f + __expf(-x)); }
__device__ __forceinline__ float tanh_(float x){
  float e = __expf(-2.0f*fabsf(x));
  float t = (1.0f - e)/(1.0f + e);
  return x < 0.0f ? -t : t;
}

// ---------------- weight reorder (all f32): W[tap][cin][co] so co-rows broadcast from SGPRs
__global__ __launch_bounds__(256) void k_wprep(
    const float* __restrict__ zw, const float* __restrict__ rw,
    const float* __restrict__ qw, const float* __restrict__ d1w,
    const float* __restrict__ c1w, const float* __restrict__ d2w,
    const float* __restrict__ d3w,
    float* __restrict__ W1, float* __restrict__ W2, float* __restrict__ W3,
    float* __restrict__ Wd2, float* __restrict__ Wd3)
{
  const int N1 = 9*65*64, N2 = 9*65*32, N3 = 9*32*64, N4 = 32*64, N5 = 64*256;
  int i = blockIdx.x*256 + threadIdx.x;
  if (i < N1){
    int tc = i >> 6, co = i & 63;
    int tap = tc / 65, cin = tc % 65;
    float v = (co < 32) ? zw[(size_t)(co*65 + cin)*9 + tap]
                        : rw[(size_t)((co-32)*65 + cin)*9 + tap];
    W1[i] = v;
  } else if (i < N1 + N2){
    int j = i - N1;
    int tc = j >> 5, co = j & 31;
    int tap = tc / 65, cin = tc % 65;
    W2[j] = qw[(size_t)(co*65 + cin)*9 + tap];
  } else if (i < N1 + N2 + N3){
    int j = i - (N1 + N2);
    int tc = j >> 6, co = j & 63;
    int tap = tc >> 5, cin = tc & 31;
    float v = (co < 32) ? d1w[(size_t)(co*32 + cin)*9 + tap]
                        : c1w[(size_t)((co-32)*32 + cin)*9 + tap];
    W3[j] = v;
  } else if (i < N1 + N2 + N3 + N4){
    int j = i - (N1 + N2 + N3);
    int cin = j >> 6, co = j & 63;
    Wd2[j] = d2w[co*32 + cin];
  } else if (i < N1 + N2 + N3 + N4 + N5){
    int j = i - (N1 + N2 + N3 + N4);
    int cin = j >> 8, co = j & 255;
    Wd3[j] = d3w[co*64 + cin];
  }
}

// Conv kernels: round-0 chassis (pixel-per-thread, tap-outer, weights via
// s_load SGPR operands, unroll 1 — REQUIRED: >64 weight f32s live breaks the
// 102-SGPR budget and falls back to vector weight loads, round-6 regression).
// Round-7 lever: manual v_cur/v_next input software-pipeline (+2 VGPR) so the
// 64-FMA block covers the next input load's latency. gru2 pairs iterations
// (2x32 weights = 64 SGPRs, legal). XCD band swizzle kept.

// ---------------- GRU part 1: conv(hx) -> z(32) | r(32); store z and r*hidden planes
__global__ __launch_bounds__(256) void k_gru1(
    const float* __restrict__ hidden, const float* __restrict__ ndp,
    const float* __restrict__ corr, const float* __restrict__ W1,
    const float* __restrict__ zb, const float* __restrict__ rb,
    float* __restrict__ zpl, float* __restrict__ rhpl)
{
  int bid = blockIdx.x;
  int pb = (bid & 7)*160 + (bid >> 3);
  int p = pb*256 + threadIdx.x;
  int row = p / WDT;
  int x = p - row*WDT;
  int yimg = row & (HGT-1);
  int b = row >> 8;
  size_t hbase = (size_t)b*32*HWSZ + (size_t)(p - b*HWSZ);
  float acc[64];
  #pragma unroll
  for (int i=0;i<64;++i) acc[i]=0.f;
  #pragma unroll
  for (int ty=0; ty<3; ++ty){
    int dy = ty-1;
    if ((unsigned)(yimg+dy) >= (unsigned)HGT) continue;   // uniform per wave
    #pragma unroll
    for (int tx=0; tx<3; ++tx){
      int dx = tx-1;
      bool okx = (unsigned)(x+dx) < (unsigned)WDT;
      int off = dy*WDT + dx;
      const float* wt = W1 + (ty*3+tx)*65*64;
      {
        float vc = okx ? hidden[hbase + off] : 0.f;      // c = 0
        #pragma unroll 1
        for (int c=0;c<32;++c){
          int cn = (c+1)&31;                             // wrap: harmless dup load
          float vn = okx ? hidden[hbase + (size_t)cn*HWSZ + off] : 0.f;
          const float* w = wt + c*64;
          #pragma unroll
          for (int i=0;i<64;++i) acc[i] = fmaf(w[i], vc, acc[i]);
          vc = vn;
        }
      }
      {
        float v = okx ? ndp[p + off] : 0.f;
        const float* w = wt + 32*64;
        #pragma unroll
        for (int i=0;i<64;++i) acc[i] = fmaf(w[i], v, acc[i]);
      }
      {
        float vc = okx ? corr[hbase + off] : 0.f;
        #pragma unroll 1
        for (int c=0;c<32;++c){
          int cn = (c+1)&31;
          float vn = okx ? corr[hbase + (size_t)cn*HWSZ + off] : 0.f;
          const float* w = wt + (33+c)*64;
          #pragma unroll
          for (int i=0;i<64;++i) acc[i] = fmaf(w[i], vc, acc[i]);
          vc = vn;
        }
      }
    }
  }
  #pragma unroll
  for (int c=0;c<32;++c)
    zpl[(size_t)c*NPIX + p] = sigm(acc[c] + zb[c]);
  #pragma unroll
  for (int c=0;c<32;++c){
    float r = sigm(acc[32+c] + rb[c]);
    rhpl[(size_t)c*NPIX + p] = r * hidden[hbase + (size_t)c*HWSZ];
  }
}

// ---------------- GRU part 2: q = tanh(conv([rh,nd,corr])); h = (1-z)h + z q -> d_out (NCHW)
__global__ __launch_bounds__(256) void k_gru2(
    const float* __restrict__ hidden, const float* __restrict__ ndp,
    const float* __restrict__ corr, const float* __restrict__ rhpl,
    const float* __restrict__ zpl, const float* __restrict__ W2,
    const float* __restrict__ qb, float* __restrict__ out_h)
{
  int bid = blockIdx.x;
  int pb = (bid & 7)*160 + (bid >> 3);
  int p = pb*256 + threadIdx.x;
  int row = p / WDT;
  int x = p - row*WDT;
  int yimg = row & (HGT-1);
  int b = row >> 8;
  size_t hbase = (size_t)b*32*HWSZ + (size_t)(p - b*HWSZ);
  float acc[32];
  #pragma unroll
  for (int i=0;i<32;++i) acc[i]=0.f;
  #pragma unroll
  for (int ty=0; ty<3; ++ty){
    int dy = ty-1;
    if ((unsigned)(yimg+dy) >= (unsigned)HGT) continue;
    #pragma unroll
    for (int tx=0; tx<3; ++tx){
      int dx = tx-1;
      bool okx = (unsigned)(x+dx) < (unsigned)WDT;
      int off = dy*WDT + dx;
      const float* wt = W2 + (ty*3+tx)*65*32;
      {
        float v0 = okx ? rhpl[p + off] : 0.f;                       // c=0
        float v1 = okx ? rhpl[(size_t)NPIX + p + off] : 0.f;        // c=1
        #pragma unroll 1
        for (int c=0;c<32;c+=2){
          int c2 = (c+2)&31, c3 = (c+3)&31;
          float v2 = okx ? rhpl[(size_t)c2*NPIX + p + off] : 0.f;
          float v3 = okx ? rhpl[(size_t)c3*NPIX + p + off] : 0.f;
          const float* w0 = wt + c*32;
          const float* w1 = wt + (c+1)*32;
          #pragma unroll
          for (int i=0;i<32;++i) acc[i] = fmaf(w0[i], v0, acc[i]);
          #pragma unroll
          for (int i=0;i<32;++i) acc[i] = fmaf(w1[i], v1, acc[i]);
          v0 = v2; v1 = v3;
        }
      }
      {
        float v = okx ? ndp[p + off] : 0.f;
        const float* w = wt + 32*32;
        #pragma unroll
        for (int i=0;i<32;++i) acc[i] = fmaf(w[i], v, acc[i]);
      }
      {
        float v0 = okx ? corr[hbase + off] : 0.f;
        float v1 = okx ? corr[hbase + HWSZ + off] : 0.f;
        #pragma unroll 1
        for (int c=0;c<32;c+=2){
          int c2 = (c+2)&31, c3 = (c+3)&31;
          float v2 = okx ? corr[hbase + (size_t)c2*HWSZ + off] : 0.f;
          float v3 = okx ? corr[hbase + (size_t)c3*HWSZ + off] : 0.f;
          const float* w0 = wt + (33+c)*32;
          const float* w1 = wt + (34+c)*32;
          #pragma unroll
          for (int i=0;i<32;++i) acc[i] = fmaf(w0[i], v0, acc[i]);
          #pragma unroll
          for (int i=0;i<32;++i) acc[i] = fmaf(w1[i], v1, acc[i]);
          v0 = v2; v1 = v3;
        }
      }
    }
  }
  #pragma unroll
  for (int c=0;c<32;++c){
    float qv = tanh_(acc[c] + qb[c]);
    float z  = zpl[(size_t)c*NPIX + p];
    float h0 = hidden[hbase + (size_t)c*HWSZ];
    out_h[hbase + (size_t)c*HWSZ] = (1.0f - z)*h0 + z*qv;
  }
}

// ---------------- heads conv: [dh1|ch1] 3x3 dil2 on h; t1 plane + conf/conf0
__global__ __launch_bounds__(256) void k_heads(
    const float* __restrict__ out_h, const float* __restrict__ W3,
    const float* __restrict__ c2w, const float* __restrict__ c2b,
    float* __restrict__ t1pl, float* __restrict__ out_conf, float* __restrict__ out_conf0)
{
  int bid = blockIdx.x;
  int pb = (bid & 7)*160 + (bid >> 3);
  int p = pb*256 + threadIdx.x;
  int row = p / WDT;
  int x = p - row*WDT;
  int yimg = row & (HGT-1);
  int b = row >> 8;
  size_t hbase = (size_t)b*32*HWSZ + (size_t)(p - b*HWSZ);
  float acc[64];
  #pragma unroll
  for (int i=0;i<64;++i) acc[i]=0.f;
  #pragma unroll
  for (int ty=0; ty<3; ++ty){
    int dy = (ty-1)*2;
    if ((unsigned)(yimg+dy) >= (unsigned)HGT) continue;
    #pragma unroll
    for (int tx=0; tx<3; ++tx){
      int dx = (tx-1)*2;
      bool okx = (unsigned)(x+dx) < (unsigned)WDT;
      int off = dy*WDT + dx;
      const float* wt = W3 + (ty*3+tx)*32*64;
      float vc = okx ? out_h[hbase + off] : 0.f;       // c = 0
      #pragma unroll 1
      for (int c=0;c<32;++c){
        int cn = (c+1)&31;
        float vn = okx ? out_h[hbase + (size_t)cn*HWSZ + off] : 0.f;
        const float* w = wt + c*64;
        #pragma unroll
        for (int i=0;i<64;++i) acc[i] = fmaf(w[i], vc, acc[i]);
        vc = vn;
      }
    }
  }
  #pragma unroll
  for (int c=0;c<32;++c)
    t1pl[(size_t)c*NPIX + p] = fmaxf(acc[c], 0.f);
  float conf0 = c2b[0];
  #pragma unroll
  for (int i=0;i<32;++i)
    conf0 = fmaf(fmaxf(acc[32+i], 0.f), c2w[i], conf0);
  out_conf0[p] = conf0;
  out_conf[p]  = sigm(conf0);
}

// ---------------- depth tail: t2 = relu(Wd2 t1); logits = Wd3 t2 + b; softmax/argmax/nd
// Weight addresses wave-uniform via readfirstlane -> s_load broadcast.
__global__ __launch_bounds__(256) void k_depth(
    const float* __restrict__ t1pl, const float* __restrict__ Wd2,
    const float* __restrict__ Wd3, const float* __restrict__ d3b,
    float* __restrict__ out_prob, float* __restrict__ out_nd)
{
  __shared__ float t2l[64][65];
  __shared__ float redA[4][64];
  __shared__ int   redI[4][64];
  __shared__ float redB[4][64];
  __shared__ float redC[4][64];
  int tid = threadIdx.x, lane = tid & 63;
  int wvu = __builtin_amdgcn_readfirstlane(tid >> 6);
  int p = blockIdx.x*64 + lane;
  float a1[16];
  #pragma unroll
  for (int i=0;i<16;++i) a1[i]=0.f;
  const float* Wd2b = Wd2 + wvu*16;
  #pragma unroll 2
  for (int c=0;c<32;++c){
    float v = t1pl[(size_t)c*NPIX + p];
    const float* w = Wd2b + c*64;
    #pragma unroll
    for (int i=0;i<16;++i) a1[i] = fmaf(w[i], v, a1[i]);
  }
  #pragma unroll
  for (int i=0;i<16;++i) t2l[lane][wvu*16+i] = fmaxf(a1[i], 0.f);
  __syncthreads();
  float acc[64];
  #pragma unroll
  for (int i=0;i<64;++i) acc[i]=0.f;
  const float* Wd3b = Wd3 + wvu*64;
  #pragma unroll 2
  for (int c=0;c<64;++c){
    float v = t2l[lane][c];
    const float* w = Wd3b + c*256;
    #pragma unroll
    for (int i=0;i<64;++i) acc[i] = fmaf(w[i], v, acc[i]);
  }
  const float* bb = d3b + wvu*64;
  float mx = -1e30f; int am = 0;
  #pragma unroll
  for (int i=0;i<64;++i){
    float l = acc[i] + bb[i];
    acc[i] = l;
    if (l > mx){ mx = l; am = wvu*64+i; }
  }
  redA[wvu][lane] = mx; redI[wvu][lane] = am;
  __syncthreads();
  float gmx = redA[0][lane]; int gam = redI[0][lane];
  #pragma unroll
  for (int w2=1; w2<4; ++w2){
    float m = redA[w2][lane]; int a = redI[w2][lane];
    if (m > gmx || (m == gmx && a < gam)){ gmx = m; gam = a; }
  }
  float s = 0.f;
  #pragma unroll
  for (int i=0;i<64;++i){
    float e = __expf(acc[i] - gmx);
    acc[i] = e; s += e;
  }
  redB[wvu][lane] = s;
  __syncthreads();
  float gs = redB[0][lane] + redB[1][lane] + redB[2][lane] + redB[3][lane];
  float inv = 1.0f / gs;
  int b = p / HWSZ;
  int qq = p - b*HWSZ;
  size_t obase = (size_t)b*256*HWSZ + qq;
  int lo = gam - 4, hi = gam + 4;
  float num = 0.f, den = 0.f;
  #pragma unroll
  for (int i=0;i<64;++i){
    int m = wvu*64 + i;
    float pr = acc[i] * inv;
    out_prob[obase + (size_t)m*HWSZ] = pr;
    int mlt = (m >= lo && m <= hi) ? 1 : 0;
    if (m == 0 && lo < 0) mlt = 1 - lo;
    if (m == 255 && hi > 255) mlt = hi - 254;
    num += (float)(m*mlt) * pr;
    den += (float)mlt * pr;
  }
  redA[wvu][lane] = num; redC[wvu][lane] = den;
  __syncthreads();
  if (wvu == 0){
    float tn = redA[0][lane]+redA[1][lane]+redA[2][lane]+redA[3][lane];
    float td = redC[0][lane]+redC[1][lane]+redC[2][lane]+redC[3][lane];
    out_nd[p] = (tn / (1e-6f + td)) * (1.0f/255.0f);
  }
}

extern "C" void kernel_launch(void* const* d_in, const int* in_sizes, int n_in,
                              void* d_out, int out_size, void* d_ws, size_t ws_size,
                              hipStream_t stream)
{
  const float* hidden = (const float*)d_in[0];
  const float* ndp    = (const float*)d_in[1];
  const float* corr   = (const float*)d_in[2];
  const float* zw  = (const float*)d_in[3];
  const float* zb  = (const float*)d_in[4];
  const float* rw  = (const float*)d_in[5];
  const float* rb  = (const float*)d_in[6];
  const float* qw  = (const float*)d_in[7];
  const float* qb  = (const float*)d_in[8];
  const float* d1w = (const float*)d_in[9];
  const float* d2w = (const float*)d_in[10];
  const float* d3w = (const float*)d_in[11];
  const float* d3b = (const float*)d_in[12];
  const float* c1w = (const float*)d_in[13];
  const float* c2w = (const float*)d_in[14];
  const float* c2b = (const float*)d_in[15];
  float* out = (float*)d_out;

  float* ws   = (float*)d_ws;
  float* zpl  = ws;                   // 10,485,760 f32
  float* rhpl = ws + 10485760;        // 10,485,760
  float* t1pl = ws + 20971520;        // 10,485,760
  float* W1   = ws + 31457280;        // 37,440
  float* W2   = W1 + 37440;           // 18,720
  float* W3   = W2 + 18720;           // 18,432
  float* Wd2  = W3 + 18432;           // 2,048
  float* Wd3  = Wd2 + 2048;           // 16,384

  float* out_h     = out;
  float* out_nd    = out + 10485760;
  float* out_prob  = out + 10813440;
  float* out_conf  = out + 94699520;
  float* out_conf0 = out + 95027200;

  k_wprep<<<364, 256, 0, stream>>>(zw, rw, qw, d1w, c1w, d2w, d3w, W1, W2, W3, Wd2, Wd3);
  k_gru1 <<<NPIX/256, 256, 0, stream>>>(hidden, ndp, corr, W1, zb, rb, zpl, rhpl);
  k_gru2 <<<NPIX/256, 256, 0, stream>>>(hidden, ndp, corr, rhpl, zpl, W2, qb, out_h);
  k_heads<<<NPIX/256, 256, 0, stream>>>(out_h, W3, c2w, c2b, t1pl, out_conf, out_conf0);
  k_depth<<<NPIX/64, 256, 0, stream>>>(t1pl, Wd2, Wd3, d3b, out_prob, out_nd);
}